// Round 1
// baseline (423.822 us; speedup 1.0000x reference)
//
#include <hip/hip_runtime.h>

typedef __attribute__((ext_vector_type(8))) short short8;
typedef __attribute__((ext_vector_type(4))) float floatx4;
typedef unsigned short ushortt;

#define LOG2E 1.4426950408889634f

__device__ __forceinline__ float bf2f(ushortt h) {
    return __uint_as_float(((unsigned int)h) << 16);
}
__device__ __forceinline__ ushortt f2bf(float f) {
    unsigned int u = __float_as_uint(f);
    u += 0x7fffu + ((u >> 16) & 1u);   // round-to-nearest-even
    return (ushortt)(u >> 16);
}

__device__ __forceinline__ float block_sum(float v, float* red) {
    #pragma unroll
    for (int off = 32; off > 0; off >>= 1) v += __shfl_down(v, off);
    int wid = threadIdx.x >> 6, ln = threadIdx.x & 63;
    __syncthreads();
    if (ln == 0) red[wid] = v;
    __syncthreads();
    return red[0] + red[1] + red[2] + red[3];
}

// ---------------------------------------------------------------------------
// sigma = ||W @ normalize(W^T u)||  (one block per matrix)
// ---------------------------------------------------------------------------
__global__ __launch_bounds__(256) void sigma_kernel(
    const float* __restrict__ Wf, const float* __restrict__ uf,
    const float* __restrict__ Wg, const float* __restrict__ ug,
    const float* __restrict__ Wh, const float* __restrict__ uh,
    const float* __restrict__ Wv, const float* __restrict__ uv,
    float* __restrict__ sig) {
    __shared__ float tv[512];
    __shared__ float red[4];
    const int mat = blockIdx.x, tid = threadIdx.x;
    const float* W; const float* u; int R, Cc;
    if (mat == 0)      { W = Wf; u = uf; R = 64;  Cc = 512; }
    else if (mat == 1) { W = Wg; u = ug; R = 64;  Cc = 512; }
    else if (mat == 2) { W = Wh; u = uh; R = 64;  Cc = 512; }
    else               { W = Wv; u = uv; R = 512; Cc = 64;  }

    for (int c = tid; c < Cc; c += 256) {
        float s = 0.f;
        for (int r = 0; r < R; ++r) s += W[r * Cc + c] * u[r];
        tv[c] = s;
    }
    __syncthreads();
    float p = 0.f;
    for (int c = tid; c < Cc; c += 256) p += tv[c] * tv[c];
    float nt2 = block_sum(p, red);
    float nt = fmaxf(sqrtf(nt2), 1e-12f);

    float zp = 0.f;
    for (int r = tid; r < R; r += 256) {
        float s = 0.f;
        for (int c = 0; c < Cc; ++c) s += W[r * Cc + c] * tv[c];
        zp += s * s;
    }
    float z2 = block_sum(zp, red);
    if (tid == 0) sig[mat] = sqrtf(z2) / nt;
}

// ---------------------------------------------------------------------------
// Pre-scale weights by 1/sigma, convert to bf16.
// wqkv: [192][512] = concat(Wf,Wg,Wh) rows;  wvb: [512][64]
// ---------------------------------------------------------------------------
__global__ __launch_bounds__(256) void prep_w_kernel(
    const float* __restrict__ Wf, const float* __restrict__ Wg,
    const float* __restrict__ Wh, const float* __restrict__ Wv,
    const float* __restrict__ sig,
    ushortt* __restrict__ wqkv, ushortt* __restrict__ wvb) {
    int idx = blockIdx.x * 256 + threadIdx.x;
    if (idx < 98304) {
        int k = idx >> 9, c = idx & 511;
        int which = k >> 6;
        const float* W = (which == 0) ? Wf : ((which == 1) ? Wg : Wh);
        float inv = 1.0f / sig[which];
        wqkv[idx] = f2bf(W[(k & 63) * 512 + c] * inv);
    } else {
        int o = idx - 98304;
        float inv = 1.0f / sig[3];
        wvb[o] = f2bf(Wv[o] * inv);
    }
}

// ---------------------------------------------------------------------------
// Fused Q/K/V projection:  Q[b][n][k] = sum_c x[b][c][n] * Wsn[k][c] + bias[k]
// Per WG: one batch, 64 pixels (n) x all 192 output channels. MFMA 16x16x32.
// A-operand = x^T tile staged transposed in LDS (bf16), B = wqkv rows (global).
// ---------------------------------------------------------------------------
__global__ __launch_bounds__(256) void qkv_kernel(
    const float* __restrict__ x, const ushortt* __restrict__ wqkv,
    const float* __restrict__ bfv, const float* __restrict__ bgv,
    const float* __restrict__ bhv,
    ushortt* __restrict__ Qb, ushortt* __restrict__ Kb, ushortt* __restrict__ Vb) {
    __shared__ ushortt Xt[64 * 72];            // [n][c] transposed tile, +8 pad
    const int tid = threadIdx.x;
    const int n0 = blockIdx.x * 64, b = blockIdx.y;
    const int w = tid >> 6, lane = tid & 63, q = lane >> 4, l15 = lane & 15;
    const int nn = tid & 63, grp = tid >> 6;   // staging role

    floatx4 acc[12];
    #pragma unroll
    for (int kt = 0; kt < 12; ++kt) acc[kt] = (floatx4){0.f, 0.f, 0.f, 0.f};

    for (int c0 = 0; c0 < 512; c0 += 64) {
        __syncthreads();
        // stage x^T: thread reads 2 c-rows at column n, packs bf16 pair
        #pragma unroll
        for (int i = 0; i < 8; ++i) {
            int cp = grp * 8 + i, c = 2 * cp;
            float u0 = x[((size_t)(b * 512 + c0 + c)) * 4096 + n0 + nn];
            float u1 = x[((size_t)(b * 512 + c0 + c + 1)) * 4096 + n0 + nn];
            unsigned int pk = (unsigned int)f2bf(u0) | ((unsigned int)f2bf(u1) << 16);
            *reinterpret_cast<unsigned int*>(&Xt[nn * 72 + c]) = pk;
        }
        __syncthreads();
        #pragma unroll
        for (int kc = 0; kc < 2; ++kc) {
            short8 a = *reinterpret_cast<const short8*>(&Xt[(16 * w + l15) * 72 + kc * 32 + q * 8]);
            #pragma unroll
            for (int kt = 0; kt < 12; ++kt) {
                short8 bb = *reinterpret_cast<const short8*>(
                    &wqkv[(size_t)(kt * 16 + l15) * 512 + c0 + kc * 32 + q * 8]);
                acc[kt] = __builtin_amdgcn_mfma_f32_16x16x32_bf16(a, bb, acc[kt], 0, 0, 0);
            }
        }
    }
    // epilogue: bias + store bf16 [b][n][64]
    #pragma unroll
    for (int kt = 0; kt < 12; ++kt) {
        int which = kt >> 2;
        const float* bias = (which == 0) ? bfv : ((which == 1) ? bgv : bhv);
        ushortt* dst = (which == 0) ? Qb : ((which == 1) ? Kb : Vb);
        int k = (kt & 3) * 16 + l15;
        float bb = bias[k];
        #pragma unroll
        for (int r = 0; r < 4; ++r) {
            int n = n0 + 16 * w + 4 * q + r;
            dst[((size_t)b * 4096 + n) * 64 + k] = f2bf(acc[kt][r] + bb);
        }
    }
}

// ---------------------------------------------------------------------------
// Flash attention: per WG one (batch, 64-row Q tile). Online softmax over
// 64-wide KV blocks. Wave w owns rows 16w..16w+15. No scale, softmax over keys.
// ---------------------------------------------------------------------------
__global__ __launch_bounds__(256) void attn_kernel(
    const ushortt* __restrict__ Qb, const ushortt* __restrict__ Kb,
    const ushortt* __restrict__ Vb, ushortt* __restrict__ Ob) {
    __shared__ ushortt Qs[64 * 72], Ks[64 * 72], Vts[64 * 72], Ps[64 * 72];
    const int tid = threadIdx.x;
    const int n0 = blockIdx.x * 64, b = blockIdx.y;
    const int w = tid >> 6, lane = tid & 63, q = lane >> 4, l15 = lane & 15;
    const ushortt* Qg = Qb + ((size_t)b * 4096 + n0) * 64;
    const ushortt* Kg = Kb + (size_t)b * 4096 * 64;
    const ushortt* Vg = Vb + (size_t)b * 4096 * 64;

    {   // stage Q tile (rows 64 x 64 bf16)
        int row = tid >> 2, seg = tid & 3;
        const uint4* src = reinterpret_cast<const uint4*>(Qg + row * 64 + seg * 16);
        uint4 v0 = src[0], v1 = src[1];
        *reinterpret_cast<uint4*>(&Qs[row * 72 + seg * 16]) = v0;
        *reinterpret_cast<uint4*>(&Qs[row * 72 + seg * 16 + 8]) = v1;
    }
    __syncthreads();
    short8 aq0 = *reinterpret_cast<const short8*>(&Qs[(16 * w + l15) * 72 + q * 8]);
    short8 aq1 = *reinterpret_cast<const short8*>(&Qs[(16 * w + l15) * 72 + 32 + q * 8]);

    floatx4 o[4];
    #pragma unroll
    for (int t = 0; t < 4; ++t) o[t] = (floatx4){0.f, 0.f, 0.f, 0.f};
    float m_i[4] = {-1e30f, -1e30f, -1e30f, -1e30f};
    float l_i[4] = {0.f, 0.f, 0.f, 0.f};

    for (int kb = 0; kb < 64; ++kb) {
        const int nb = kb * 64;
        __syncthreads();   // prev-iter reads of Ks/Vts complete
        {   // stage K tile
            int row = tid >> 2, seg = tid & 3;
            const uint4* src = reinterpret_cast<const uint4*>(Kg + (size_t)(nb + row) * 64 + seg * 16);
            uint4 v0 = src[0], v1 = src[1];
            *reinterpret_cast<uint4*>(&Ks[row * 72 + seg * 16]) = v0;
            *reinterpret_cast<uint4*>(&Ks[row * 72 + seg * 16 + 8]) = v1;
            // stage V transposed: Vts[d][n]
            int p = tid & 31, g = tid >> 5;
            union { uint4 v; ushortt h[8]; } ra, rb;
            ra.v = *reinterpret_cast<const uint4*>(Vg + (size_t)(nb + 2 * p) * 64 + g * 8);
            rb.v = *reinterpret_cast<const uint4*>(Vg + (size_t)(nb + 2 * p + 1) * 64 + g * 8);
            #pragma unroll
            for (int j = 0; j < 8; ++j) {
                unsigned int pk = (unsigned int)ra.h[j] | ((unsigned int)rb.h[j] << 16);
                *reinterpret_cast<unsigned int*>(&Vts[(g * 8 + j) * 72 + 2 * p]) = pk;
            }
        }
        __syncthreads();

        // S = Q K^T  (wave strip: 16 rows x 64 cols)
        floatx4 s[4];
        #pragma unroll
        for (int t = 0; t < 4; ++t) {
            s[t] = (floatx4){0.f, 0.f, 0.f, 0.f};
            short8 bk0 = *reinterpret_cast<const short8*>(&Ks[(16 * t + l15) * 72 + q * 8]);
            short8 bk1 = *reinterpret_cast<const short8*>(&Ks[(16 * t + l15) * 72 + 32 + q * 8]);
            s[t] = __builtin_amdgcn_mfma_f32_16x16x32_bf16(aq0, bk0, s[t], 0, 0, 0);
            s[t] = __builtin_amdgcn_mfma_f32_16x16x32_bf16(aq1, bk1, s[t], 0, 0, 0);
        }

        // online softmax (row r lives in reg r across the 16 lanes of a quad)
        float alpha[4];
        #pragma unroll
        for (int r = 0; r < 4; ++r) {
            float mx = fmaxf(fmaxf(s[0][r], s[1][r]), fmaxf(s[2][r], s[3][r]));
            #pragma unroll
            for (int off = 8; off > 0; off >>= 1) mx = fmaxf(mx, __shfl_xor(mx, off));
            float mn = fmaxf(m_i[r], mx);
            alpha[r] = exp2f((m_i[r] - mn) * LOG2E);
            m_i[r] = mn;
            float rs = 0.f;
            #pragma unroll
            for (int t = 0; t < 4; ++t) {
                float pv = exp2f((s[t][r] - mn) * LOG2E);
                s[t][r] = pv;
                rs += pv;
            }
            #pragma unroll
            for (int off = 8; off > 0; off >>= 1) rs += __shfl_xor(rs, off);
            l_i[r] = l_i[r] * alpha[r] + rs;
        }
        // P (C-layout) -> LDS -> A-layout; strip is wave-private, no barrier
        #pragma unroll
        for (int t = 0; t < 4; ++t)
            #pragma unroll
            for (int r = 0; r < 4; ++r)
                Ps[(16 * w + 4 * q + r) * 72 + 16 * t + l15] = f2bf(s[t][r]);
        // rescale O
        #pragma unroll
        for (int r = 0; r < 4; ++r) {
            o[0][r] *= alpha[r]; o[1][r] *= alpha[r];
            o[2][r] *= alpha[r]; o[3][r] *= alpha[r];
        }
        // O += P V
        short8 ap0 = *reinterpret_cast<const short8*>(&Ps[(16 * w + l15) * 72 + q * 8]);
        short8 ap1 = *reinterpret_cast<const short8*>(&Ps[(16 * w + l15) * 72 + 32 + q * 8]);
        #pragma unroll
        for (int dt = 0; dt < 4; ++dt) {
            short8 bv0 = *reinterpret_cast<const short8*>(&Vts[(16 * dt + l15) * 72 + q * 8]);
            short8 bv1 = *reinterpret_cast<const short8*>(&Vts[(16 * dt + l15) * 72 + 32 + q * 8]);
            o[dt] = __builtin_amdgcn_mfma_f32_16x16x32_bf16(ap0, bv0, o[dt], 0, 0, 0);
            o[dt] = __builtin_amdgcn_mfma_f32_16x16x32_bf16(ap1, bv1, o[dt], 0, 0, 0);
        }
    }
    // epilogue: O/l, store bf16 [b][n][64]
    ushortt* Og = Ob + ((size_t)b * 4096 + n0) * 64;
    #pragma unroll
    for (int r = 0; r < 4; ++r) {
        float inv = 1.0f / l_i[r];
        int nrow = 16 * w + 4 * q + r;
        #pragma unroll
        for (int dt = 0; dt < 4; ++dt)
            Og[nrow * 64 + 16 * dt + l15] = f2bf(o[dt][r] * inv);
    }
}

// ---------------------------------------------------------------------------
// out[b][c][n] = gamma*( sum_k Wv_sn[c][k]*O[b][n][k] + bv[c] ) + x[b][c][n]
// Per WG: 64 c x 64 n, K=64 (2 MFMA k-chunks). No LDS needed.
// ---------------------------------------------------------------------------
__global__ __launch_bounds__(256) void proj_kernel(
    const ushortt* __restrict__ Ob, const ushortt* __restrict__ wvb,
    const float* __restrict__ bv, const float* __restrict__ gamma,
    const float* __restrict__ x, float* __restrict__ out) {
    const int tid = threadIdx.x;
    const int n0 = blockIdx.x * 64, c0 = blockIdx.y * 64, b = blockIdx.z;
    const int w = tid >> 6, lane = tid & 63, q = lane >> 4, l15 = lane & 15;

    short8 a0 = *reinterpret_cast<const short8*>(&wvb[(size_t)(c0 + 16 * w + l15) * 64 + q * 8]);
    short8 a1 = *reinterpret_cast<const short8*>(&wvb[(size_t)(c0 + 16 * w + l15) * 64 + 32 + q * 8]);
    floatx4 acc[4];
    #pragma unroll
    for (int t = 0; t < 4; ++t) acc[t] = (floatx4){0.f, 0.f, 0.f, 0.f};
    #pragma unroll
    for (int t = 0; t < 4; ++t) {
        const ushortt* ob = Ob + ((size_t)b * 4096 + n0 + 16 * t + l15) * 64;
        short8 b0 = *reinterpret_cast<const short8*>(ob + q * 8);
        short8 b1 = *reinterpret_cast<const short8*>(ob + 32 + q * 8);
        acc[t] = __builtin_amdgcn_mfma_f32_16x16x32_bf16(a0, b0, acc[t], 0, 0, 0);
        acc[t] = __builtin_amdgcn_mfma_f32_16x16x32_bf16(a1, b1, acc[t], 0, 0, 0);
    }
    float gm = gamma[0];
    #pragma unroll
    for (int t = 0; t < 4; ++t) {
        #pragma unroll
        for (int r = 0; r < 4; ++r) {
            int c = c0 + 16 * w + 4 * q + r;
            int n = n0 + 16 * t + l15;
            size_t idx = ((size_t)(b * 512 + c)) * 4096 + n;
            out[idx] = gm * (acc[t][r] + bv[c]) + x[idx];
        }
    }
}

// ---------------------------------------------------------------------------
extern "C" void kernel_launch(void* const* d_in, const int* in_sizes, int n_in,
                              void* d_out, int out_size, void* d_ws, size_t ws_size,
                              hipStream_t stream) {
    const float* x   = (const float*)d_in[0];
    const float* Wf  = (const float*)d_in[1];
    const float* bf_ = (const float*)d_in[2];
    const float* Wg  = (const float*)d_in[3];
    const float* bg_ = (const float*)d_in[4];
    const float* Wh  = (const float*)d_in[5];
    const float* bh_ = (const float*)d_in[6];
    const float* Wv  = (const float*)d_in[7];
    const float* bv_ = (const float*)d_in[8];
    const float* uf  = (const float*)d_in[9];
    const float* ug  = (const float*)d_in[10];
    const float* uh  = (const float*)d_in[11];
    const float* uv  = (const float*)d_in[12];
    const float* gm  = (const float*)d_in[13];
    float* out = (float*)d_out;

    char* ws = (char*)d_ws;
    float* sig     = (float*)ws;                       // 16 B (256 reserved)
    ushortt* wqkv  = (ushortt*)(ws + 256);             // 192*512*2 = 196608
    ushortt* wvb   = (ushortt*)(ws + 256 + 196608);    // 512*64*2  = 65536
    ushortt* Qb    = (ushortt*)(ws + 262400);          // 4*4096*64*2 each
    ushortt* Kb    = Qb + (size_t)4 * 4096 * 64;
    ushortt* Vb    = Kb + (size_t)4 * 4096 * 64;
    ushortt* Ob    = Vb + (size_t)4 * 4096 * 64;
    // total ws needed: 262400 + 4*2097152 = 8651008 bytes

    sigma_kernel<<<4, 256, 0, stream>>>(Wf, uf, Wg, ug, Wh, uh, Wv, uv, sig);
    prep_w_kernel<<<512, 256, 0, stream>>>(Wf, Wg, Wh, Wv, sig, wqkv, wvb);
    qkv_kernel<<<dim3(64, 4), 256, 0, stream>>>(x, wqkv, bf_, bg_, bh_, Qb, Kb, Vb);
    attn_kernel<<<dim3(64, 4), 256, 0, stream>>>(Qb, Kb, Vb, Ob);
    proj_kernel<<<dim3(64, 8, 4), 256, 0, stream>>>(Ob, wvb, bv_, gm, x, out);
}

// Round 2
// 271.008 us; speedup vs baseline: 1.5639x; 1.5639x over previous
//
#include <hip/hip_runtime.h>

typedef __attribute__((ext_vector_type(8))) short short8;
typedef __attribute__((ext_vector_type(4))) float floatx4;
typedef unsigned short ushortt;

#define LOG2E 1.4426950408889634f

__device__ __forceinline__ ushortt f2bf(float f) {
    unsigned int u = __float_as_uint(f);
    u += 0x7fffu + ((u >> 16) & 1u);   // round-to-nearest-even
    return (ushortt)(u >> 16);
}

__device__ __forceinline__ float block_sum(float v, float* red) {
    #pragma unroll
    for (int off = 32; off > 0; off >>= 1) v += __shfl_down(v, off);
    int wid = threadIdx.x >> 6, ln = threadIdx.x & 63;
    __syncthreads();
    if (ln == 0) red[wid] = v;
    __syncthreads();
    return red[0] + red[1] + red[2] + red[3];
}

// ---------------------------------------------------------------------------
// sigma = ||W @ normalize(W^T u)||   (one block per matrix, coalesced)
// ---------------------------------------------------------------------------
__global__ __launch_bounds__(256) void sigma_kernel(
    const float* __restrict__ Wf, const float* __restrict__ uf,
    const float* __restrict__ Wg, const float* __restrict__ ug,
    const float* __restrict__ Wh, const float* __restrict__ uh,
    const float* __restrict__ Wv, const float* __restrict__ uv,
    float* __restrict__ sig) {
    __shared__ float tv[512];
    __shared__ float tvp[256];
    __shared__ float red[4];
    const int mat = blockIdx.x, tid = threadIdx.x;
    const int wave = tid >> 6, lane = tid & 63;

    if (mat < 3) {  // W: [64][512]
        const float* W = (mat == 0) ? Wf : ((mat == 1) ? Wg : Wh);
        const float* u = (mat == 0) ? uf : ((mat == 1) ? ug : uh);
        // phase 1: tv[c] = sum_r W[r][c] u[r]  (coalesced over c)
        for (int c = tid; c < 512; c += 256) {
            float s0 = 0.f;
            #pragma unroll 8
            for (int r = 0; r < 64; ++r) s0 += W[r * 512 + c] * u[r];
            tv[c] = s0;
        }
        __syncthreads();
        float p = tv[tid] * tv[tid] + tv[tid + 256] * tv[tid + 256];
        float nt2 = block_sum(p, red);
        float nt = fmaxf(sqrtf(nt2), 1e-12f);
        // phase 2: per-wave rows, coalesced over c, butterfly reduce
        float z2p = 0.f;
        for (int rr = wave; rr < 64; rr += 4) {
            float part = 0.f;
            #pragma unroll
            for (int j = 0; j < 8; ++j) {
                int c = lane + 64 * j;
                part += W[rr * 512 + c] * tv[c];
            }
            #pragma unroll
            for (int off = 32; off > 0; off >>= 1) part += __shfl_xor(part, off);
            z2p += part * part;
        }
        __syncthreads();
        if (lane == 0) red[wave] = z2p;
        __syncthreads();
        if (tid == 0) {
            float z2 = red[0] + red[1] + red[2] + red[3];
            sig[mat] = sqrtf(z2) / nt;
        }
    } else {        // Wv: [512][64]
        const float* W = Wv; const float* u = uv;
        // phase 1: tv[c] = sum_r W[r][c] u[r], 4 row-segments in parallel
        {
            int c = tid & 63, rs = tid >> 6;
            float s0 = 0.f;
            #pragma unroll 8
            for (int r = rs * 128; r < rs * 128 + 128; ++r) s0 += W[r * 64 + c] * u[r];
            tvp[tid] = s0;
        }
        __syncthreads();
        if (tid < 64) tv[tid] = tvp[tid] + tvp[tid + 64] + tvp[tid + 128] + tvp[tid + 192];
        __syncthreads();
        float t = (tid < 64) ? tv[tid] : 0.f;
        float nt2 = block_sum(t * t, red);
        float nt = fmaxf(sqrtf(nt2), 1e-12f);
        // phase 2: 512 rows, one row per wave-iter (64 c's = 64 lanes)
        float z2p = 0.f;
        for (int rr = wave; rr < 512; rr += 4) {
            float part = W[rr * 64 + lane] * tv[lane];
            #pragma unroll
            for (int off = 32; off > 0; off >>= 1) part += __shfl_xor(part, off);
            z2p += part * part;
        }
        __syncthreads();
        if (lane == 0) red[wave] = z2p;
        __syncthreads();
        if (tid == 0) {
            float z2 = red[0] + red[1] + red[2] + red[3];
            sig[3] = sqrtf(z2) / nt;
        }
    }
}

// ---------------------------------------------------------------------------
// Pre-scale weights by 1/sigma, convert to bf16.
// wqkv: [192][512] = concat(Wf,Wg,Wh) rows;  wvb: [512][64]
// ---------------------------------------------------------------------------
__global__ __launch_bounds__(256) void prep_w_kernel(
    const float* __restrict__ Wf, const float* __restrict__ Wg,
    const float* __restrict__ Wh, const float* __restrict__ Wv,
    const float* __restrict__ sig,
    ushortt* __restrict__ wqkv, ushortt* __restrict__ wvb) {
    int idx = blockIdx.x * 256 + threadIdx.x;
    if (idx < 98304) {
        int k = idx >> 9, c = idx & 511;
        int which = k >> 6;
        const float* W = (which == 0) ? Wf : ((which == 1) ? Wg : Wh);
        float inv = 1.0f / sig[which];
        wqkv[idx] = f2bf(W[(k & 63) * 512 + c] * inv);
    } else {
        int o = idx - 98304;
        float inv = 1.0f / sig[3];
        wvb[o] = f2bf(Wv[o] * inv);
    }
}

// ---------------------------------------------------------------------------
// Fused Q/K/V projection. 512 threads: waves 0-3 compute k-outputs 0-95,
// waves 4-7 compute 96-191 (same x-tile) -> 8 waves/CU.
// ---------------------------------------------------------------------------
__global__ __launch_bounds__(512) void qkv_kernel(
    const float* __restrict__ x, const ushortt* __restrict__ wqkv,
    const float* __restrict__ bfv, const float* __restrict__ bgv,
    const float* __restrict__ bhv,
    ushortt* __restrict__ Qb, ushortt* __restrict__ Kb, ushortt* __restrict__ Vb) {
    __shared__ ushortt Xt[64 * 72];            // [n][c] transposed tile, padded
    const int tid = threadIdx.x;
    const int n0 = blockIdx.x * 64, b = blockIdx.y;
    const int w8 = tid >> 6, lane = tid & 63, q = lane >> 4, l15 = lane & 15;
    const int wr = w8 & 3, khalf = w8 >> 2;
    const int nn = tid & 63, grp = tid >> 6;   // staging role (8 groups)

    floatx4 acc[6];
    #pragma unroll
    for (int kt = 0; kt < 6; ++kt) acc[kt] = (floatx4){0.f, 0.f, 0.f, 0.f};

    for (int c0 = 0; c0 < 512; c0 += 64) {
        __syncthreads();
        #pragma unroll
        for (int i = 0; i < 4; ++i) {
            int cp = grp * 4 + i, c = 2 * cp;
            float u0 = x[((size_t)(b * 512 + c0 + c)) * 4096 + n0 + nn];
            float u1 = x[((size_t)(b * 512 + c0 + c + 1)) * 4096 + n0 + nn];
            unsigned int pk = (unsigned int)f2bf(u0) | ((unsigned int)f2bf(u1) << 16);
            *reinterpret_cast<unsigned int*>(&Xt[nn * 72 + c]) = pk;
        }
        __syncthreads();
        #pragma unroll
        for (int kc = 0; kc < 2; ++kc) {
            short8 a = *reinterpret_cast<const short8*>(&Xt[(16 * wr + l15) * 72 + kc * 32 + q * 8]);
            #pragma unroll
            for (int kt = 0; kt < 6; ++kt) {
                short8 bb = *reinterpret_cast<const short8*>(
                    &wqkv[(size_t)(khalf * 96 + kt * 16 + l15) * 512 + c0 + kc * 32 + q * 8]);
                acc[kt] = __builtin_amdgcn_mfma_f32_16x16x32_bf16(a, bb, acc[kt], 0, 0, 0);
            }
        }
    }
    #pragma unroll
    for (int kt = 0; kt < 6; ++kt) {
        int kt_g = khalf * 6 + kt;
        int which = kt_g >> 2;
        const float* bias = (which == 0) ? bfv : ((which == 1) ? bgv : bhv);
        ushortt* dst = (which == 0) ? Qb : ((which == 1) ? Kb : Vb);
        int k = (kt_g & 3) * 16 + l15;
        float bb = bias[k];
        #pragma unroll
        for (int r = 0; r < 4; ++r) {
            int n = n0 + 16 * wr + 4 * q + r;
            dst[((size_t)b * 4096 + n) * 64 + k] = f2bf(acc[kt][r] + bb);
        }
    }
}

// ---------------------------------------------------------------------------
// Flash attention with KV split. Computes S^T = K Q^T so softmax reductions
// are mostly in-register; P exits with 4 consecutive k's per lane (b64 LDS
// writes). grid = (64 q-tiles, 4 batch, S splits). S==1 -> write Ob directly.
// ---------------------------------------------------------------------------
__global__ __launch_bounds__(256) void attn_kernel(
    const ushortt* __restrict__ Qb, const ushortt* __restrict__ Kb,
    const ushortt* __restrict__ Vb, float* __restrict__ Opart,
    float2* __restrict__ ml, ushortt* __restrict__ Ob, int KB) {
    __shared__ ushortt Ks[64 * 72], Vts[64 * 72], Ps[64 * 72];
    const int tid = threadIdx.x;
    const int n0 = blockIdx.x * 64, b = blockIdx.y, s = blockIdx.z;
    const int w = tid >> 6, lane = tid & 63, q = lane >> 4, l15 = lane & 15;
    const ushortt* Qg = Qb + ((size_t)b * 4096 + n0) * 64;
    const ushortt* Kg = Kb + (size_t)b * 4096 * 64;
    const ushortt* Vg = Vb + (size_t)b * 4096 * 64;

    // Q fragment (B-operand of S^T): lane l15 holds Q row 16w+l15
    short8 bq0 = *reinterpret_cast<const short8*>(Qg + (16 * w + l15) * 64 + q * 8);
    short8 bq1 = *reinterpret_cast<const short8*>(Qg + (16 * w + l15) * 64 + 32 + q * 8);

    floatx4 o[4];
    #pragma unroll
    for (int t = 0; t < 4; ++t) o[t] = (floatx4){0.f, 0.f, 0.f, 0.f};
    float m_i = -1e30f, l_i = 0.f;

    const int kb0 = s * KB;
    for (int kb = kb0; kb < kb0 + KB; ++kb) {
        const int nb = kb * 64;
        __syncthreads();
        {   // stage K rows + V transposed
            int row = tid >> 2, seg = tid & 3;
            const uint4* src = reinterpret_cast<const uint4*>(Kg + (size_t)(nb + row) * 64 + seg * 16);
            uint4 v0 = src[0], v1 = src[1];
            *reinterpret_cast<uint4*>(&Ks[row * 72 + seg * 16]) = v0;
            *reinterpret_cast<uint4*>(&Ks[row * 72 + seg * 16 + 8]) = v1;
            int p = tid & 31, g = tid >> 5;
            union { uint4 v; ushortt h[8]; } ra, rb;
            ra.v = *reinterpret_cast<const uint4*>(Vg + (size_t)(nb + 2 * p) * 64 + g * 8);
            rb.v = *reinterpret_cast<const uint4*>(Vg + (size_t)(nb + 2 * p + 1) * 64 + g * 8);
            #pragma unroll
            for (int j = 0; j < 8; ++j) {
                unsigned int pk = (unsigned int)ra.h[j] | ((unsigned int)rb.h[j] << 16);
                *reinterpret_cast<unsigned int*>(&Vts[(g * 8 + j) * 72 + 2 * p]) = pk;
            }
        }
        __syncthreads();

        // S^T = K Q^T : lane holds S^T[key=16t+4q+r][nq=16w+l15]
        floatx4 st[4];
        #pragma unroll
        for (int t = 0; t < 4; ++t) {
            st[t] = (floatx4){0.f, 0.f, 0.f, 0.f};
            short8 ak0 = *reinterpret_cast<const short8*>(&Ks[(16 * t + l15) * 72 + q * 8]);
            short8 ak1 = *reinterpret_cast<const short8*>(&Ks[(16 * t + l15) * 72 + 32 + q * 8]);
            st[t] = __builtin_amdgcn_mfma_f32_16x16x32_bf16(ak0, bq0, st[t], 0, 0, 0);
            st[t] = __builtin_amdgcn_mfma_f32_16x16x32_bf16(ak1, bq1, st[t], 0, 0, 0);
        }

        // online softmax over the column nq = 16w+l15 (16 in-lane + cross-quad)
        float mx = -1e30f;
        #pragma unroll
        for (int t = 0; t < 4; ++t)
            #pragma unroll
            for (int r = 0; r < 4; ++r) mx = fmaxf(mx, st[t][r]);
        mx = fmaxf(mx, __shfl_xor(mx, 16));
        mx = fmaxf(mx, __shfl_xor(mx, 32));
        float mn = fmaxf(m_i, mx);
        float alpha = exp2f((m_i - mn) * LOG2E);
        m_i = mn;
        float rs = 0.f;
        #pragma unroll
        for (int t = 0; t < 4; ++t)
            #pragma unroll
            for (int r = 0; r < 4; ++r) {
                float pv = exp2f((st[t][r] - mn) * LOG2E);
                st[t][r] = pv;
                rs += pv;
            }
        rs += __shfl_xor(rs, 16);
        rs += __shfl_xor(rs, 32);
        l_i = l_i * alpha + rs;

        // P^T -> Ps in A-layout: lane writes row 16w+l15, cols 16t+4q..+3 (b64)
        #pragma unroll
        for (int t = 0; t < 4; ++t) {
            unsigned int lo = (unsigned int)f2bf(st[t][0]) | ((unsigned int)f2bf(st[t][1]) << 16);
            unsigned int hi = (unsigned int)f2bf(st[t][2]) | ((unsigned int)f2bf(st[t][3]) << 16);
            uint2 pk; pk.x = lo; pk.y = hi;
            *reinterpret_cast<uint2*>(&Ps[(16 * w + l15) * 72 + 16 * t + 4 * q]) = pk;
        }

        // broadcast alpha from col-layout (lane 4q+r) to row-layout, rescale O
        float ar[4];
        #pragma unroll
        for (int r = 0; r < 4; ++r) ar[r] = __shfl(alpha, 4 * q + r);
        #pragma unroll
        for (int dt = 0; dt < 4; ++dt)
            #pragma unroll
            for (int r = 0; r < 4; ++r) o[dt][r] *= ar[r];

        // O += P V
        short8 ap0 = *reinterpret_cast<const short8*>(&Ps[(16 * w + l15) * 72 + q * 8]);
        short8 ap1 = *reinterpret_cast<const short8*>(&Ps[(16 * w + l15) * 72 + 32 + q * 8]);
        #pragma unroll
        for (int dt = 0; dt < 4; ++dt) {
            short8 bv0 = *reinterpret_cast<const short8*>(&Vts[(16 * dt + l15) * 72 + q * 8]);
            short8 bv1 = *reinterpret_cast<const short8*>(&Vts[(16 * dt + l15) * 72 + 32 + q * 8]);
            o[dt] = __builtin_amdgcn_mfma_f32_16x16x32_bf16(ap0, bv0, o[dt], 0, 0, 0);
            o[dt] = __builtin_amdgcn_mfma_f32_16x16x32_bf16(ap1, bv1, o[dt], 0, 0, 0);
        }
    }

    if (gridDim.z == 1) {
        // normalize directly (l_i per col-layout -> broadcast like alpha)
        float lr[4];
        #pragma unroll
        for (int r = 0; r < 4; ++r) lr[r] = 1.0f / __shfl(l_i, 4 * q + r);
        ushortt* Og = Ob + ((size_t)b * 4096 + n0) * 64;
        #pragma unroll
        for (int dt = 0; dt < 4; ++dt)
            #pragma unroll
            for (int r = 0; r < 4; ++r)
                Og[(16 * w + 4 * q + r) * 64 + 16 * dt + l15] = f2bf(o[dt][r] * lr[r]);
    } else {
        float* Og = Opart + (((size_t)s * 4 + b) * 4096 + n0) * 64;
        #pragma unroll
        for (int dt = 0; dt < 4; ++dt)
            #pragma unroll
            for (int r = 0; r < 4; ++r)
                Og[(16 * w + 4 * q + r) * 64 + 16 * dt + l15] = o[dt][r];
        if (q == 0) {
            float2 v; v.x = m_i; v.y = l_i;
            ml[((size_t)s * 4 + b) * 4096 + n0 + 16 * w + l15] = v;
        }
    }
}

// ---------------------------------------------------------------------------
// Merge KV-split partials: O = sum_s w_s O_s / sum_s w_s l_s, w_s=exp(m_s-m*)
// ---------------------------------------------------------------------------
__global__ __launch_bounds__(256) void combine_kernel(
    const float* __restrict__ Opart, const float2* __restrict__ ml,
    ushortt* __restrict__ Ob, int S) {
    const int tid = threadIdx.x;
    const int n0 = blockIdx.x * 64, b = blockIdx.y;
    const int row = n0 + (tid >> 2), dseg = tid & 3;
    float2 mls[4];
    float m = -1e30f;
    for (int s = 0; s < S; ++s) {
        mls[s] = ml[((size_t)s * 4 + b) * 4096 + row];
        m = fmaxf(m, mls[s].x);
    }
    float wgt[4], denom = 0.f;
    for (int s = 0; s < S; ++s) {
        wgt[s] = exp2f((mls[s].x - m) * LOG2E);
        denom += wgt[s] * mls[s].y;
    }
    float inv = 1.0f / denom;
    float acc[16];
    #pragma unroll
    for (int j = 0; j < 16; ++j) acc[j] = 0.f;
    for (int s = 0; s < S; ++s) {
        const float4* op = reinterpret_cast<const float4*>(
            Opart + (((size_t)s * 4 + b) * 4096 + row) * 64 + dseg * 16);
        float ww = wgt[s];
        #pragma unroll
        for (int c = 0; c < 4; ++c) {
            float4 v = op[c];
            acc[4 * c + 0] += ww * v.x; acc[4 * c + 1] += ww * v.y;
            acc[4 * c + 2] += ww * v.z; acc[4 * c + 3] += ww * v.w;
        }
    }
    union { uint4 u[2]; ushortt h[16]; } pk;
    #pragma unroll
    for (int j = 0; j < 16; ++j) pk.h[j] = f2bf(acc[j] * inv);
    uint4* dst = reinterpret_cast<uint4*>(Ob + ((size_t)b * 4096 + row) * 64 + dseg * 16);
    dst[0] = pk.u[0]; dst[1] = pk.u[1];
}

// ---------------------------------------------------------------------------
// out[b][c][n] = gamma*( sum_k Wv_sn[c][k]*O[b][n][k] + bv[c] ) + x[b][c][n]
// ---------------------------------------------------------------------------
__global__ __launch_bounds__(256) void proj_kernel(
    const ushortt* __restrict__ Ob, const ushortt* __restrict__ wvb,
    const float* __restrict__ bv, const float* __restrict__ gamma,
    const float* __restrict__ x, float* __restrict__ out) {
    const int tid = threadIdx.x;
    const int n0 = blockIdx.x * 64, c0 = blockIdx.y * 64, b = blockIdx.z;
    const int w = tid >> 6, lane = tid & 63, q = lane >> 4, l15 = lane & 15;

    short8 a0 = *reinterpret_cast<const short8*>(&wvb[(size_t)(c0 + 16 * w + l15) * 64 + q * 8]);
    short8 a1 = *reinterpret_cast<const short8*>(&wvb[(size_t)(c0 + 16 * w + l15) * 64 + 32 + q * 8]);
    floatx4 acc[4];
    #pragma unroll
    for (int t = 0; t < 4; ++t) acc[t] = (floatx4){0.f, 0.f, 0.f, 0.f};
    #pragma unroll
    for (int t = 0; t < 4; ++t) {
        const ushortt* ob = Ob + ((size_t)b * 4096 + n0 + 16 * t + l15) * 64;
        short8 b0 = *reinterpret_cast<const short8*>(ob + q * 8);
        short8 b1 = *reinterpret_cast<const short8*>(ob + 32 + q * 8);
        acc[t] = __builtin_amdgcn_mfma_f32_16x16x32_bf16(a0, b0, acc[t], 0, 0, 0);
        acc[t] = __builtin_amdgcn_mfma_f32_16x16x32_bf16(a1, b1, acc[t], 0, 0, 0);
    }
    float gm = gamma[0];
    #pragma unroll
    for (int t = 0; t < 4; ++t) {
        #pragma unroll
        for (int r = 0; r < 4; ++r) {
            int c = c0 + 16 * w + 4 * q + r;
            int n = n0 + 16 * t + l15;
            size_t idx = ((size_t)(b * 512 + c)) * 4096 + n;
            out[idx] = gm * (acc[t][r] + bv[c]) + x[idx];
        }
    }
}

// ---------------------------------------------------------------------------
extern "C" void kernel_launch(void* const* d_in, const int* in_sizes, int n_in,
                              void* d_out, int out_size, void* d_ws, size_t ws_size,
                              hipStream_t stream) {
    const float* x   = (const float*)d_in[0];
    const float* Wf  = (const float*)d_in[1];
    const float* bf_ = (const float*)d_in[2];
    const float* Wg  = (const float*)d_in[3];
    const float* bg_ = (const float*)d_in[4];
    const float* Wh  = (const float*)d_in[5];
    const float* bh_ = (const float*)d_in[6];
    const float* Wv  = (const float*)d_in[7];
    const float* bv_ = (const float*)d_in[8];
    const float* uf  = (const float*)d_in[9];
    const float* ug  = (const float*)d_in[10];
    const float* uh  = (const float*)d_in[11];
    const float* uv  = (const float*)d_in[12];
    const float* gm  = (const float*)d_in[13];
    float* out = (float*)d_out;

    char* ws = (char*)d_ws;
    float*   sig   = (float*)ws;                         // 256 B reserved
    ushortt* wqkv  = (ushortt*)(ws + 256);               // 196608
    ushortt* wvb   = (ushortt*)(ws + 196864);            // 65536
    ushortt* Qb    = (ushortt*)(ws + 262400);            // 2 MB
    ushortt* Kb    = (ushortt*)(ws + 2359552);           // 2 MB
    ushortt* Vb    = (ushortt*)(ws + 4456704);           // 2 MB
    ushortt* Ob    = (ushortt*)(ws + 6553856);           // 2 MB
    float2*  ml    = (float2*)(ws + 8651008);            // up to 512 KB
    float*   Opart = (float*)(ws + 9175296);             // up to 16 MB

    // choose KV-split factor by available workspace
    int S = 1;
    if (ws_size >= (size_t)9175296 + (size_t)4 * 4194304) S = 4;
    else if (ws_size >= (size_t)9175296 + (size_t)2 * 4194304) S = 2;

    sigma_kernel<<<4, 256, 0, stream>>>(Wf, uf, Wg, ug, Wh, uh, Wv, uv, sig);
    prep_w_kernel<<<512, 256, 0, stream>>>(Wf, Wg, Wh, Wv, sig, wqkv, wvb);
    qkv_kernel<<<dim3(64, 4), 512, 0, stream>>>(x, wqkv, bf_, bg_, bh_, Qb, Kb, Vb);
    attn_kernel<<<dim3(64, 4, S), 256, 0, stream>>>(Qb, Kb, Vb, Opart, ml, Ob, 64 / S);
    if (S > 1) combine_kernel<<<dim3(64, 4), 256, 0, stream>>>(Opart, ml, Ob, S);
    proj_kernel<<<dim3(64, 8, 4), 256, 0, stream>>>(Ob, wvb, bv_, gm, x, out);
}

// Round 3
// 264.112 us; speedup vs baseline: 1.6047x; 1.0261x over previous
//
#include <hip/hip_runtime.h>
#include <hip/hip_bf16.h>

typedef __attribute__((ext_vector_type(8))) short short8;
typedef __attribute__((ext_vector_type(4))) float floatx4;
typedef unsigned short ushortt;

#define LOG2E 1.4426950408889634f

__device__ __forceinline__ ushortt f2bf(float f) {
    unsigned int u = __float_as_uint(f);
    u += 0x7fffu + ((u >> 16) & 1u);   // round-to-nearest-even
    return (ushortt)(u >> 16);
}
// packed 2xfp32 -> 2xbf16 (v_cvt_pk_bf16_f32 on gfx950)
__device__ __forceinline__ unsigned int f2bf_pk(float a, float b) {
    float2 t; t.x = a; t.y = b;
    __hip_bfloat162 h = __float22bfloat162_rn(t);
    return *reinterpret_cast<unsigned int*>(&h);
}

__device__ __forceinline__ float block_sum(float v, float* red) {
    #pragma unroll
    for (int off = 32; off > 0; off >>= 1) v += __shfl_down(v, off);
    int wid = threadIdx.x >> 6, ln = threadIdx.x & 63;
    __syncthreads();
    if (ln == 0) red[wid] = v;
    __syncthreads();
    return red[0] + red[1] + red[2] + red[3];
}

// ---------------------------------------------------------------------------
// sigma = ||W @ normalize(W^T u)||   (one block per matrix, coalesced)
// ---------------------------------------------------------------------------
__global__ __launch_bounds__(256) void sigma_kernel(
    const float* __restrict__ Wf, const float* __restrict__ uf,
    const float* __restrict__ Wg, const float* __restrict__ ug,
    const float* __restrict__ Wh, const float* __restrict__ uh,
    const float* __restrict__ Wv, const float* __restrict__ uv,
    float* __restrict__ sig) {
    __shared__ float tv[512];
    __shared__ float tvp[256];
    __shared__ float red[4];
    const int mat = blockIdx.x, tid = threadIdx.x;
    const int wave = tid >> 6, lane = tid & 63;

    if (mat < 3) {  // W: [64][512]
        const float* W = (mat == 0) ? Wf : ((mat == 1) ? Wg : Wh);
        const float* u = (mat == 0) ? uf : ((mat == 1) ? ug : uh);
        for (int c = tid; c < 512; c += 256) {
            float s0 = 0.f;
            #pragma unroll 8
            for (int r = 0; r < 64; ++r) s0 += W[r * 512 + c] * u[r];
            tv[c] = s0;
        }
        __syncthreads();
        float p = tv[tid] * tv[tid] + tv[tid + 256] * tv[tid + 256];
        float nt2 = block_sum(p, red);
        float nt = fmaxf(sqrtf(nt2), 1e-12f);
        float z2p = 0.f;
        for (int rr = wave; rr < 64; rr += 4) {
            float part = 0.f;
            #pragma unroll
            for (int j = 0; j < 8; ++j) {
                int c = lane + 64 * j;
                part += W[rr * 512 + c] * tv[c];
            }
            #pragma unroll
            for (int off = 32; off > 0; off >>= 1) part += __shfl_xor(part, off);
            z2p += part * part;
        }
        __syncthreads();
        if (lane == 0) red[wave] = z2p;
        __syncthreads();
        if (tid == 0) {
            float z2 = red[0] + red[1] + red[2] + red[3];
            sig[mat] = sqrtf(z2) / nt;
        }
    } else {        // Wv: [512][64]
        const float* W = Wv; const float* u = uv;
        {
            int c = tid & 63, rs = tid >> 6;
            float s0 = 0.f;
            #pragma unroll 8
            for (int r = rs * 128; r < rs * 128 + 128; ++r) s0 += W[r * 64 + c] * u[r];
            tvp[tid] = s0;
        }
        __syncthreads();
        if (tid < 64) tv[tid] = tvp[tid] + tvp[tid + 64] + tvp[tid + 128] + tvp[tid + 192];
        __syncthreads();
        float t = (tid < 64) ? tv[tid] : 0.f;
        float nt2 = block_sum(t * t, red);
        float nt = fmaxf(sqrtf(nt2), 1e-12f);
        float z2p = 0.f;
        for (int rr = wave; rr < 512; rr += 4) {
            float part = W[rr * 64 + lane] * tv[lane];
            #pragma unroll
            for (int off = 32; off > 0; off >>= 1) part += __shfl_xor(part, off);
            z2p += part * part;
        }
        __syncthreads();
        if (lane == 0) red[wave] = z2p;
        __syncthreads();
        if (tid == 0) {
            float z2 = red[0] + red[1] + red[2] + red[3];
            sig[3] = sqrtf(z2) / nt;
        }
    }
}

// ---------------------------------------------------------------------------
// Pre-scale weights by 1/sigma, convert to bf16.
// ---------------------------------------------------------------------------
__global__ __launch_bounds__(256) void prep_w_kernel(
    const float* __restrict__ Wf, const float* __restrict__ Wg,
    const float* __restrict__ Wh, const float* __restrict__ Wv,
    const float* __restrict__ sig,
    ushortt* __restrict__ wqkv, ushortt* __restrict__ wvb) {
    int idx = blockIdx.x * 256 + threadIdx.x;
    if (idx < 98304) {
        int k = idx >> 9, c = idx & 511;
        int which = k >> 6;
        const float* W = (which == 0) ? Wf : ((which == 1) ? Wg : Wh);
        float inv = 1.0f / sig[which];
        wqkv[idx] = f2bf(W[(k & 63) * 512 + c] * inv);
    } else {
        int o = idx - 98304;
        float inv = 1.0f / sig[3];
        wvb[o] = f2bf(Wv[o] * inv);
    }
}

// ---------------------------------------------------------------------------
// Fused Q/K/V projection. grid (64 n-tiles, 4 b, 2 khalf), 256 threads.
// khalf 0: Q rows 0..63 + K rows 0..31;  khalf 1: K rows 32..63 + V (all).
// V is written PRE-TRANSPOSED to Vt[b][d][n] via an LDS bounce.
// ---------------------------------------------------------------------------
__global__ __launch_bounds__(256) void qkv_kernel(
    const float* __restrict__ x, const ushortt* __restrict__ wqkv,
    const float* __restrict__ bfv, const float* __restrict__ bgv,
    const float* __restrict__ bhv,
    ushortt* __restrict__ Qb, ushortt* __restrict__ Kb, ushortt* __restrict__ Vt) {
    __shared__ ushortt Xt[64 * 72];            // [n][c] tile; reused as V [k][n]
    const int tid = threadIdx.x;
    const int n0 = blockIdx.x * 64, b = blockIdx.y, khalf = blockIdx.z;
    const int wr = tid >> 6, lane = tid & 63, q = lane >> 4, l15 = lane & 15;
    const int nn = tid & 63, grp = tid >> 6;

    floatx4 acc[6];
    #pragma unroll
    for (int kt = 0; kt < 6; ++kt) acc[kt] = (floatx4){0.f, 0.f, 0.f, 0.f};

    for (int c0 = 0; c0 < 512; c0 += 64) {
        __syncthreads();
        #pragma unroll
        for (int i = 0; i < 8; ++i) {
            int c = 2 * (grp * 8 + i);
            float u0 = x[((size_t)(b * 512 + c0 + c)) * 4096 + n0 + nn];
            float u1 = x[((size_t)(b * 512 + c0 + c + 1)) * 4096 + n0 + nn];
            *reinterpret_cast<unsigned int*>(&Xt[nn * 72 + c]) = f2bf_pk(u0, u1);
        }
        __syncthreads();
        #pragma unroll
        for (int kc = 0; kc < 2; ++kc) {
            short8 a = *reinterpret_cast<const short8*>(&Xt[(16 * wr + l15) * 72 + kc * 32 + q * 8]);
            #pragma unroll
            for (int kt = 0; kt < 6; ++kt) {
                short8 bb = *reinterpret_cast<const short8*>(
                    &wqkv[(size_t)(khalf * 96 + kt * 16 + l15) * 512 + c0 + kc * 32 + q * 8]);
                acc[kt] = __builtin_amdgcn_mfma_f32_16x16x32_bf16(a, bb, acc[kt], 0, 0, 0);
            }
        }
    }

    if (khalf == 0) {
        #pragma unroll
        for (int kt = 0; kt < 6; ++kt) {
            int which = kt >> 2;                       // kt 0..3 -> Q, 4..5 -> K
            const float* bias = (which == 0) ? bfv : bgv;
            ushortt* dst = (which == 0) ? Qb : Kb;
            int k = (kt & 3) * 16 + l15;
            float bb = bias[k];
            #pragma unroll
            for (int r = 0; r < 4; ++r) {
                int n = n0 + 16 * wr + 4 * q + r;
                dst[((size_t)b * 4096 + n) * 64 + k] = f2bf(acc[kt][r] + bb);
            }
        }
    } else {
        #pragma unroll
        for (int kt = 0; kt < 2; ++kt) {               // K rows 32..63
            int k = (kt + 2) * 16 + l15;
            float bb = bgv[k];
            #pragma unroll
            for (int r = 0; r < 4; ++r) {
                int n = n0 + 16 * wr + 4 * q + r;
                Kb[((size_t)b * 4096 + n) * 64 + k] = f2bf(acc[kt][r] + bb);
            }
        }
        __syncthreads();                               // done reading Xt
        #pragma unroll
        for (int kt = 2; kt < 6; ++kt) {               // V -> LDS [k][n]
            int k = (kt - 2) * 16 + l15;
            float bb = bhv[k];
            uint2 pk;
            pk.x = f2bf_pk(acc[kt][0] + bb, acc[kt][1] + bb);
            pk.y = f2bf_pk(acc[kt][2] + bb, acc[kt][3] + bb);
            *reinterpret_cast<uint2*>(&Xt[k * 72 + 16 * wr + 4 * q]) = pk;
        }
        __syncthreads();
        {   // coalesced copy LDS -> Vt[b][d][n]
            int k = tid >> 2, seg = tid & 3;
            uint4 a0 = *reinterpret_cast<const uint4*>(&Xt[k * 72 + seg * 16]);
            uint4 a1 = *reinterpret_cast<const uint4*>(&Xt[k * 72 + seg * 16 + 8]);
            uint4* dst = reinterpret_cast<uint4*>(Vt + ((size_t)(b * 64 + k)) * 4096 + n0 + seg * 16);
            dst[0] = a0; dst[1] = a1;
        }
    }
}

// ---------------------------------------------------------------------------
// Flash attention with KV split; S^T = K Q^T; V read pre-transposed.
// ---------------------------------------------------------------------------
__global__ __launch_bounds__(256) void attn_kernel(
    const ushortt* __restrict__ Qb, const ushortt* __restrict__ Kb,
    const ushortt* __restrict__ Vt, float* __restrict__ Opart,
    float2* __restrict__ ml, ushortt* __restrict__ Ob, int KB) {
    __shared__ ushortt Ks[64 * 72], Vts[64 * 72], Ps[64 * 72];
    const int tid = threadIdx.x;
    const int n0 = blockIdx.x * 64, b = blockIdx.y, s = blockIdx.z;
    const int w = tid >> 6, lane = tid & 63, q = lane >> 4, l15 = lane & 15;
    const ushortt* Qg = Qb + ((size_t)b * 4096 + n0) * 64;
    const ushortt* Kg = Kb + (size_t)b * 4096 * 64;
    const ushortt* Vg = Vt + (size_t)b * 64 * 4096;

    short8 bq0 = *reinterpret_cast<const short8*>(Qg + (16 * w + l15) * 64 + q * 8);
    short8 bq1 = *reinterpret_cast<const short8*>(Qg + (16 * w + l15) * 64 + 32 + q * 8);

    floatx4 o[4];
    #pragma unroll
    for (int t = 0; t < 4; ++t) o[t] = (floatx4){0.f, 0.f, 0.f, 0.f};
    float m_i = -1e30f, l_i = 0.f;

    const int row = tid >> 2, seg = tid & 3;   // staging roles
    const int kb0 = s * KB;
    for (int kb = kb0; kb < kb0 + KB; ++kb) {
        const int nb = kb * 64;
        __syncthreads();
        {   // stage K rows + Vt rows (both natural-layout b128 copies)
            const uint4* srck = reinterpret_cast<const uint4*>(Kg + (size_t)(nb + row) * 64 + seg * 16);
            uint4 k0 = srck[0], k1 = srck[1];
            const uint4* srcv = reinterpret_cast<const uint4*>(Vg + (size_t)row * 4096 + nb + seg * 16);
            uint4 v0 = srcv[0], v1 = srcv[1];
            *reinterpret_cast<uint4*>(&Ks[row * 72 + seg * 16]) = k0;
            *reinterpret_cast<uint4*>(&Ks[row * 72 + seg * 16 + 8]) = k1;
            *reinterpret_cast<uint4*>(&Vts[row * 72 + seg * 16]) = v0;
            *reinterpret_cast<uint4*>(&Vts[row * 72 + seg * 16 + 8]) = v1;
        }
        __syncthreads();

        // S^T = K Q^T : lane holds S^T[key=16t+4q+r][nq=16w+l15]
        floatx4 st[4];
        #pragma unroll
        for (int t = 0; t < 4; ++t) {
            st[t] = (floatx4){0.f, 0.f, 0.f, 0.f};
            short8 ak0 = *reinterpret_cast<const short8*>(&Ks[(16 * t + l15) * 72 + q * 8]);
            short8 ak1 = *reinterpret_cast<const short8*>(&Ks[(16 * t + l15) * 72 + 32 + q * 8]);
            st[t] = __builtin_amdgcn_mfma_f32_16x16x32_bf16(ak0, bq0, st[t], 0, 0, 0);
            st[t] = __builtin_amdgcn_mfma_f32_16x16x32_bf16(ak1, bq1, st[t], 0, 0, 0);
        }

        // online softmax over column nq (16 in-lane + 2 cross-quad shuffles)
        float mx = -1e30f;
        #pragma unroll
        for (int t = 0; t < 4; ++t)
            #pragma unroll
            for (int r = 0; r < 4; ++r) mx = fmaxf(mx, st[t][r]);
        mx = fmaxf(mx, __shfl_xor(mx, 16));
        mx = fmaxf(mx, __shfl_xor(mx, 32));
        float mn = fmaxf(m_i, mx);
        float alpha = exp2f((m_i - mn) * LOG2E);
        m_i = mn;
        float rs = 0.f;
        #pragma unroll
        for (int t = 0; t < 4; ++t)
            #pragma unroll
            for (int r = 0; r < 4; ++r) {
                float pv = exp2f((st[t][r] - mn) * LOG2E);
                st[t][r] = pv;
                rs += pv;
            }
        rs += __shfl_xor(rs, 16);
        rs += __shfl_xor(rs, 32);
        l_i = l_i * alpha + rs;

        // P^T -> Ps in A-layout (b64 writes, 4 consecutive keys per lane)
        #pragma unroll
        for (int t = 0; t < 4; ++t) {
            uint2 pk;
            pk.x = f2bf_pk(st[t][0], st[t][1]);
            pk.y = f2bf_pk(st[t][2], st[t][3]);
            *reinterpret_cast<uint2*>(&Ps[(16 * w + l15) * 72 + 16 * t + 4 * q]) = pk;
        }

        float ar[4];
        #pragma unroll
        for (int r = 0; r < 4; ++r) ar[r] = __shfl(alpha, 4 * q + r);
        #pragma unroll
        for (int dt = 0; dt < 4; ++dt)
            #pragma unroll
            for (int r = 0; r < 4; ++r) o[dt][r] *= ar[r];

        short8 ap0 = *reinterpret_cast<const short8*>(&Ps[(16 * w + l15) * 72 + q * 8]);
        short8 ap1 = *reinterpret_cast<const short8*>(&Ps[(16 * w + l15) * 72 + 32 + q * 8]);
        #pragma unroll
        for (int dt = 0; dt < 4; ++dt) {
            short8 bv0 = *reinterpret_cast<const short8*>(&Vts[(16 * dt + l15) * 72 + q * 8]);
            short8 bv1 = *reinterpret_cast<const short8*>(&Vts[(16 * dt + l15) * 72 + 32 + q * 8]);
            o[dt] = __builtin_amdgcn_mfma_f32_16x16x32_bf16(ap0, bv0, o[dt], 0, 0, 0);
            o[dt] = __builtin_amdgcn_mfma_f32_16x16x32_bf16(ap1, bv1, o[dt], 0, 0, 0);
        }
    }

    if (gridDim.z == 1) {
        float lr[4];
        #pragma unroll
        for (int r = 0; r < 4; ++r) lr[r] = 1.0f / __shfl(l_i, 4 * q + r);
        ushortt* Og = Ob + ((size_t)b * 4096 + n0) * 64;
        #pragma unroll
        for (int dt = 0; dt < 4; ++dt)
            #pragma unroll
            for (int r = 0; r < 4; ++r)
                Og[(16 * w + 4 * q + r) * 64 + 16 * dt + l15] = f2bf(o[dt][r] * lr[r]);
    } else {
        float* Og = Opart + (((size_t)s * 4 + b) * 4096 + n0) * 64;
        #pragma unroll
        for (int dt = 0; dt < 4; ++dt)
            #pragma unroll
            for (int r = 0; r < 4; ++r)
                Og[(16 * w + 4 * q + r) * 64 + 16 * dt + l15] = o[dt][r];
        if (q == 0) {
            float2 v; v.x = m_i; v.y = l_i;
            ml[((size_t)s * 4 + b) * 4096 + n0 + 16 * w + l15] = v;
        }
    }
}

// ---------------------------------------------------------------------------
// Merge KV-split partials.
// ---------------------------------------------------------------------------
__global__ __launch_bounds__(256) void combine_kernel(
    const float* __restrict__ Opart, const float2* __restrict__ ml,
    ushortt* __restrict__ Ob, int S) {
    const int tid = threadIdx.x;
    const int n0 = blockIdx.x * 64, b = blockIdx.y;
    const int row = n0 + (tid >> 2), dseg = tid & 3;
    float2 mls[4];
    float m = -1e30f;
    for (int s = 0; s < S; ++s) {
        mls[s] = ml[((size_t)s * 4 + b) * 4096 + row];
        m = fmaxf(m, mls[s].x);
    }
    float wgt[4], denom = 0.f;
    for (int s = 0; s < S; ++s) {
        wgt[s] = exp2f((mls[s].x - m) * LOG2E);
        denom += wgt[s] * mls[s].y;
    }
    float inv = 1.0f / denom;
    float acc[16];
    #pragma unroll
    for (int j = 0; j < 16; ++j) acc[j] = 0.f;
    for (int s = 0; s < S; ++s) {
        const float4* op = reinterpret_cast<const float4*>(
            Opart + (((size_t)s * 4 + b) * 4096 + row) * 64 + dseg * 16);
        float ww = wgt[s];
        #pragma unroll
        for (int c = 0; c < 4; ++c) {
            float4 v = op[c];
            acc[4 * c + 0] += ww * v.x; acc[4 * c + 1] += ww * v.y;
            acc[4 * c + 2] += ww * v.z; acc[4 * c + 3] += ww * v.w;
        }
    }
    union { uint4 u[2]; unsigned int w[8]; } pk;
    #pragma unroll
    for (int j = 0; j < 8; ++j) pk.w[j] = f2bf_pk(acc[2 * j] * inv, acc[2 * j + 1] * inv);
    uint4* dst = reinterpret_cast<uint4*>(Ob + ((size_t)b * 4096 + row) * 64 + dseg * 16);
    dst[0] = pk.u[0]; dst[1] = pk.u[1];
}

// ---------------------------------------------------------------------------
// out[b][c][n] = gamma*( sum_k Wv_sn[c][k]*O[b][n][k] + bv[c] ) + x[b][c][n]
// ---------------------------------------------------------------------------
__global__ __launch_bounds__(256) void proj_kernel(
    const ushortt* __restrict__ Ob, const ushortt* __restrict__ wvb,
    const float* __restrict__ bv, const float* __restrict__ gamma,
    const float* __restrict__ x, float* __restrict__ out) {
    const int tid = threadIdx.x;
    const int n0 = blockIdx.x * 64, c0 = blockIdx.y * 64, b = blockIdx.z;
    const int w = tid >> 6, lane = tid & 63, q = lane >> 4, l15 = lane & 15;

    short8 a0 = *reinterpret_cast<const short8*>(&wvb[(size_t)(c0 + 16 * w + l15) * 64 + q * 8]);
    short8 a1 = *reinterpret_cast<const short8*>(&wvb[(size_t)(c0 + 16 * w + l15) * 64 + 32 + q * 8]);
    floatx4 acc[4];
    #pragma unroll
    for (int t = 0; t < 4; ++t) acc[t] = (floatx4){0.f, 0.f, 0.f, 0.f};
    #pragma unroll
    for (int t = 0; t < 4; ++t) {
        const ushortt* ob = Ob + ((size_t)b * 4096 + n0 + 16 * t + l15) * 64;
        short8 b0 = *reinterpret_cast<const short8*>(ob + q * 8);
        short8 b1 = *reinterpret_cast<const short8*>(ob + 32 + q * 8);
        acc[t] = __builtin_amdgcn_mfma_f32_16x16x32_bf16(a0, b0, acc[t], 0, 0, 0);
        acc[t] = __builtin_amdgcn_mfma_f32_16x16x32_bf16(a1, b1, acc[t], 0, 0, 0);
    }
    float gm = gamma[0];
    #pragma unroll
    for (int t = 0; t < 4; ++t) {
        #pragma unroll
        for (int r = 0; r < 4; ++r) {
            int c = c0 + 16 * w + 4 * q + r;
            int n = n0 + 16 * t + l15;
            size_t idx = ((size_t)(b * 512 + c)) * 4096 + n;
            out[idx] = gm * (acc[t][r] + bv[c]) + x[idx];
        }
    }
}

// ---------------------------------------------------------------------------
extern "C" void kernel_launch(void* const* d_in, const int* in_sizes, int n_in,
                              void* d_out, int out_size, void* d_ws, size_t ws_size,
                              hipStream_t stream) {
    const float* x   = (const float*)d_in[0];
    const float* Wf  = (const float*)d_in[1];
    const float* bf_ = (const float*)d_in[2];
    const float* Wg  = (const float*)d_in[3];
    const float* bg_ = (const float*)d_in[4];
    const float* Wh  = (const float*)d_in[5];
    const float* bh_ = (const float*)d_in[6];
    const float* Wv  = (const float*)d_in[7];
    const float* bv_ = (const float*)d_in[8];
    const float* uf  = (const float*)d_in[9];
    const float* ug  = (const float*)d_in[10];
    const float* uh  = (const float*)d_in[11];
    const float* uv  = (const float*)d_in[12];
    const float* gm  = (const float*)d_in[13];
    float* out = (float*)d_out;

    char* ws = (char*)d_ws;
    float*   sig   = (float*)ws;                         // 256 B reserved
    ushortt* wqkv  = (ushortt*)(ws + 256);               // 196608
    ushortt* wvb   = (ushortt*)(ws + 196864);            // 65536
    ushortt* Qb    = (ushortt*)(ws + 262400);            // 2 MB
    ushortt* Kb    = (ushortt*)(ws + 2359552);           // 2 MB
    ushortt* Vt    = (ushortt*)(ws + 4456704);           // 2 MB  [b][d][n]
    ushortt* Ob    = (ushortt*)(ws + 6553856);           // 2 MB
    float2*  ml    = (float2*)(ws + 8651008);            // 512 KB
    float*   Opart = (float*)(ws + 9175296);             // up to 16 MB

    int S = 1;
    if (ws_size >= (size_t)9175296 + (size_t)4 * 4194304) S = 4;
    else if (ws_size >= (size_t)9175296 + (size_t)2 * 4194304) S = 2;

    sigma_kernel<<<4, 256, 0, stream>>>(Wf, uf, Wg, ug, Wh, uh, Wv, uv, sig);
    prep_w_kernel<<<512, 256, 0, stream>>>(Wf, Wg, Wh, Wv, sig, wqkv, wvb);
    qkv_kernel<<<dim3(64, 4, 2), 256, 0, stream>>>(x, wqkv, bf_, bg_, bh_, Qb, Kb, Vt);
    attn_kernel<<<dim3(64, 4, S), 256, 0, stream>>>(Qb, Kb, Vt, Opart, ml, Ob, 64 / S);
    if (S > 1) combine_kernel<<<dim3(64, 4), 256, 0, stream>>>(Opart, ml, Ob, S);
    proj_kernel<<<dim3(64, 8, 4), 256, 0, stream>>>(Ob, wvb, bv_, gm, x, out);
}

// Round 4
// 250.866 us; speedup vs baseline: 1.6894x; 1.0528x over previous
//
#include <hip/hip_runtime.h>
#include <hip/hip_bf16.h>

typedef __attribute__((ext_vector_type(8))) short short8;
typedef __attribute__((ext_vector_type(4))) float floatx4;
typedef __attribute__((ext_vector_type(16))) float floatx16;
typedef unsigned short ushortt;

#define LOG2E 1.4426950408889634f

__device__ __forceinline__ ushortt f2bf(float f) {
    unsigned int u = __float_as_uint(f);
    u += 0x7fffu + ((u >> 16) & 1u);
    return (ushortt)(u >> 16);
}
__device__ __forceinline__ unsigned int f2bf_pk(float a, float b) {
    float2 t; t.x = a; t.y = b;
    __hip_bfloat162 h = __float22bfloat162_rn(t);
    return *reinterpret_cast<unsigned int*>(&h);
}
__device__ __forceinline__ float bf2f(ushortt h) {
    return __uint_as_float(((unsigned int)h) << 16);
}

__device__ __forceinline__ float block_sum(float v, float* red) {
    #pragma unroll
    for (int off = 32; off > 0; off >>= 1) v += __shfl_down(v, off);
    int wid = threadIdx.x >> 6, ln = threadIdx.x & 63;
    __syncthreads();
    if (ln == 0) red[wid] = v;
    __syncthreads();
    return red[0] + red[1] + red[2] + red[3];
}

// ---------------------------------------------------------------------------
// sigma = ||W @ normalize(W^T u)||
// ---------------------------------------------------------------------------
__global__ __launch_bounds__(256) void sigma_kernel(
    const float* __restrict__ Wf, const float* __restrict__ uf,
    const float* __restrict__ Wg, const float* __restrict__ ug,
    const float* __restrict__ Wh, const float* __restrict__ uh,
    const float* __restrict__ Wv, const float* __restrict__ uv,
    float* __restrict__ sig) {
    __shared__ float tv[512];
    __shared__ float tvp[256];
    __shared__ float red[4];
    const int mat = blockIdx.x, tid = threadIdx.x;
    const int wave = tid >> 6, lane = tid & 63;

    if (mat < 3) {
        const float* W = (mat == 0) ? Wf : ((mat == 1) ? Wg : Wh);
        const float* u = (mat == 0) ? uf : ((mat == 1) ? ug : uh);
        for (int c = tid; c < 512; c += 256) {
            float s0 = 0.f;
            #pragma unroll 8
            for (int r = 0; r < 64; ++r) s0 += W[r * 512 + c] * u[r];
            tv[c] = s0;
        }
        __syncthreads();
        float p = tv[tid] * tv[tid] + tv[tid + 256] * tv[tid + 256];
        float nt2 = block_sum(p, red);
        float nt = fmaxf(sqrtf(nt2), 1e-12f);
        float z2p = 0.f;
        for (int rr = wave; rr < 64; rr += 4) {
            float part = 0.f;
            #pragma unroll
            for (int j = 0; j < 8; ++j) part += W[rr * 512 + lane + 64 * j] * tv[lane + 64 * j];
            #pragma unroll
            for (int off = 32; off > 0; off >>= 1) part += __shfl_xor(part, off);
            z2p += part * part;
        }
        __syncthreads();
        if (lane == 0) red[wave] = z2p;
        __syncthreads();
        if (tid == 0) sig[mat] = sqrtf(red[0] + red[1] + red[2] + red[3]) / nt;
    } else {
        const float* W = Wv; const float* u = uv;
        {
            int c = tid & 63, rs = tid >> 6;
            float s0 = 0.f;
            #pragma unroll 8
            for (int r = rs * 128; r < rs * 128 + 128; ++r) s0 += W[r * 64 + c] * u[r];
            tvp[tid] = s0;
        }
        __syncthreads();
        if (tid < 64) tv[tid] = tvp[tid] + tvp[tid + 64] + tvp[tid + 128] + tvp[tid + 192];
        __syncthreads();
        float t = (tid < 64) ? tv[tid] : 0.f;
        float nt2 = block_sum(t * t, red);
        float nt = fmaxf(sqrtf(nt2), 1e-12f);
        float z2p = 0.f;
        for (int rr = wave; rr < 512; rr += 4) {
            float part = W[rr * 64 + lane] * tv[lane];
            #pragma unroll
            for (int off = 32; off > 0; off >>= 1) part += __shfl_xor(part, off);
            z2p += part * part;
        }
        __syncthreads();
        if (lane == 0) red[wave] = z2p;
        __syncthreads();
        if (tid == 0) sig[3] = sqrtf(red[0] + red[1] + red[2] + red[3]) / nt;
    }
}

// ---------------------------------------------------------------------------
__global__ __launch_bounds__(256) void prep_w_kernel(
    const float* __restrict__ Wf, const float* __restrict__ Wg,
    const float* __restrict__ Wh, const float* __restrict__ Wv,
    const float* __restrict__ sig,
    ushortt* __restrict__ wqkv, ushortt* __restrict__ wvb) {
    int idx = blockIdx.x * 256 + threadIdx.x;
    if (idx < 98304) {
        int k = idx >> 9, c = idx & 511;
        int which = k >> 6;
        const float* W = (which == 0) ? Wf : ((which == 1) ? Wg : Wh);
        float inv = 1.0f / sig[which];
        wqkv[idx] = f2bf(W[(k & 63) * 512 + c] * inv);
    } else {
        int o = idx - 98304;
        wvb[o] = f2bf(Wv[o] / sig[3]);
    }
}

// ---------------------------------------------------------------------------
// QKV projection, 32-pixel tiles, x read once. grid (128, 4), 256 thr.
// waves: strip = w&1 (16-row halves of the 32 pixels), ksel = w>>1 (k 0..95 / 96..191)
// Q stored pre-scaled by LOG2E. V stored transposed Vt[b][d][n].
// ---------------------------------------------------------------------------
__global__ __launch_bounds__(256) void qkv_kernel(
    const float* __restrict__ x, const ushortt* __restrict__ wqkv,
    const float* __restrict__ bfv, const float* __restrict__ bgv,
    const float* __restrict__ bhv,
    ushortt* __restrict__ Qb, ushortt* __restrict__ Kb, ushortt* __restrict__ Vt) {
    __shared__ unsigned int xs[1120];          // 32 rows x 35 dwords (pad->~2-way)
    const int tid = threadIdx.x;
    const int n0 = blockIdx.x * 32, b = blockIdx.y;
    const int lane = tid & 63, w = tid >> 6;
    const int strip = w & 1, ksel = w >> 1;
    const int q = lane >> 4, l15 = lane & 15;
    const int sn = tid & 31, sg = tid >> 5;    // staging roles

    floatx4 acc[6];
    #pragma unroll
    for (int kt = 0; kt < 6; ++kt) acc[kt] = (floatx4){0.f, 0.f, 0.f, 0.f};

    const float* xb = x + ((size_t)b * 512) * 4096 + n0 + sn;
    float2 pre[4];
    #pragma unroll
    for (int i = 0; i < 4; ++i) {
        int c = sg * 8 + 2 * i;
        pre[i].x = xb[(size_t)c * 4096];
        pre[i].y = xb[(size_t)(c + 1) * 4096];
    }

    for (int c0 = 0; c0 < 512; c0 += 64) {
        __syncthreads();
        #pragma unroll
        for (int i = 0; i < 4; ++i)
            xs[sn * 35 + sg * 4 + i] = f2bf_pk(pre[i].x, pre[i].y);
        if (c0 + 64 < 512) {
            #pragma unroll
            for (int i = 0; i < 4; ++i) {
                int c = c0 + 64 + sg * 8 + 2 * i;
                pre[i].x = xb[(size_t)c * 4096];
                pre[i].y = xb[(size_t)(c + 1) * 4096];
            }
        }
        __syncthreads();
        #pragma unroll
        for (int kc = 0; kc < 2; ++kc) {
            union { unsigned int u[4]; short8 s8; } af;
            const unsigned int* p = &xs[(16 * strip + l15) * 35 + kc * 16 + q * 4];
            af.u[0] = p[0]; af.u[1] = p[1]; af.u[2] = p[2]; af.u[3] = p[3];
            #pragma unroll
            for (int kt = 0; kt < 6; ++kt) {
                short8 bb = *reinterpret_cast<const short8*>(
                    &wqkv[(size_t)(ksel * 96 + kt * 16 + l15) * 512 + c0 + kc * 32 + q * 8]);
                acc[kt] = __builtin_amdgcn_mfma_f32_16x16x32_bf16(af.s8, bb, acc[kt], 0, 0, 0);
            }
        }
    }

    const int nloc = n0 + 16 * strip + 4 * q;
    if (ksel == 0) {
        #pragma unroll
        for (int kt = 0; kt < 4; ++kt) {       // Q (exp2-domain)
            int k = kt * 16 + l15;
            float bb = bfv[k];
            #pragma unroll
            for (int r = 0; r < 4; ++r)
                Qb[((size_t)b * 4096 + nloc + r) * 64 + k] = f2bf((acc[kt][r] + bb) * LOG2E);
        }
        #pragma unroll
        for (int kt = 4; kt < 6; ++kt) {       // K rows 0..31
            int k = (kt - 4) * 16 + l15;
            float bb = bgv[k];
            #pragma unroll
            for (int r = 0; r < 4; ++r)
                Kb[((size_t)b * 4096 + nloc + r) * 64 + k] = f2bf(acc[kt][r] + bb);
        }
    } else {
        #pragma unroll
        for (int kt = 0; kt < 2; ++kt) {       // K rows 32..63
            int k = 32 + kt * 16 + l15;
            float bb = bgv[k];
            #pragma unroll
            for (int r = 0; r < 4; ++r)
                Kb[((size_t)b * 4096 + nloc + r) * 64 + k] = f2bf(acc[kt][r] + bb);
        }
    }
    __syncthreads();
    if (ksel == 1) {                           // V -> LDS [d][n/2] (stride 17 dwords)
        #pragma unroll
        for (int kt = 2; kt < 6; ++kt) {
            int d = (kt - 2) * 16 + l15;
            float bb = bhv[d];
            int base = d * 17 + 8 * strip + 2 * q;
            xs[base]     = f2bf_pk(acc[kt][0] + bb, acc[kt][1] + bb);
            xs[base + 1] = f2bf_pk(acc[kt][2] + bb, acc[kt][3] + bb);
        }
    }
    __syncthreads();
    {   // coalesced store Vt[b][d][n0..n0+31]
        int d = tid >> 2, sgg = tid & 3;
        uint4 vv;
        vv.x = xs[d * 17 + sgg * 4 + 0]; vv.y = xs[d * 17 + sgg * 4 + 1];
        vv.z = xs[d * 17 + sgg * 4 + 2]; vv.w = xs[d * 17 + sgg * 4 + 3];
        *reinterpret_cast<uint4*>(&Vt[((size_t)b * 64 + d) * 4096 + n0 + sgg * 8]) = vv;
    }
}

// ---------------------------------------------------------------------------
// Flash attention, 32x32x16 MFMA. Wave (qh,kh): 32 queries x 32 keys of each
// 64-key tile. Q register-resident (exp2-domain). P stays in registers
// (shfl-based C->B-operand transform). kh halves merged at end via LDS.
// ---------------------------------------------------------------------------
__global__ __launch_bounds__(256) void attn_kernel(
    const ushortt* __restrict__ Qb, const ushortt* __restrict__ Kb,
    const ushortt* __restrict__ Vt, ushortt* __restrict__ Opart,
    float2* __restrict__ ml, ushortt* __restrict__ Ob, int KB) {
    __shared__ unsigned int smem[4420];
    // staging: KS = smem[0..2112), VS = smem[2112..4224)  (64 rows x 33 dwords)
    // merge:   OM = smem[0..4160) (64 x 65 f32), MLm = [4160..4288), MLl = [4288..4416)
    const int tid = threadIdx.x;
    const int n0 = blockIdx.x * 64, b = blockIdx.y, s = blockIdx.z;
    const int lane = tid & 63, w = tid >> 6;
    const int qh = w & 1, kh = w >> 1;
    const int l31 = lane & 31, h = lane >> 5;

    const ushortt* Kg = Kb + (size_t)b * 4096 * 64;
    const ushortt* Vg = Vt + (size_t)b * 64 * 4096;

    // register-resident Q (B-operand): lane holds query n0+32qh+l31, d=16kc+8h+j
    short8 bq[4];
    {
        const ushortt* Qg = Qb + ((size_t)b * 4096 + n0 + 32 * qh + l31) * 64;
        #pragma unroll
        for (int kc = 0; kc < 4; ++kc)
            bq[kc] = *reinterpret_cast<const short8*>(Qg + kc * 16 + 8 * h);
    }

    floatx16 ot0 = {}, ot1 = {};
    float m_i = -1e30f, l_i = 0.f;

    const int row = tid >> 2, seg = tid & 3;   // staging roles
    const int kbeg = s * KB, kend = kbeg + KB;

    uint4 ck0, ck1, cv0, cv1;
    {
        int nb = kbeg * 64;
        const ushortt* kp = Kg + (size_t)(nb + row) * 64 + seg * 16;
        ck0 = *reinterpret_cast<const uint4*>(kp);
        ck1 = *reinterpret_cast<const uint4*>(kp + 8);
        const ushortt* vp = Vg + (size_t)row * 4096 + nb + seg * 16;
        cv0 = *reinterpret_cast<const uint4*>(vp);
        cv1 = *reinterpret_cast<const uint4*>(vp + 8);
    }

    for (int kb = kbeg; kb < kend; ++kb) {
        __syncthreads();
        {   // write prefetched tile to LDS (dword layout, stride 33)
            unsigned int* kd = &smem[row * 33 + seg * 8];
            union { uint4 v; unsigned int u[4]; } a;
            a.v = ck0; kd[0] = a.u[0]; kd[1] = a.u[1]; kd[2] = a.u[2]; kd[3] = a.u[3];
            a.v = ck1; kd[4] = a.u[0]; kd[5] = a.u[1]; kd[6] = a.u[2]; kd[7] = a.u[3];
            unsigned int* vd = &smem[2112 + row * 33 + seg * 8];
            a.v = cv0; vd[0] = a.u[0]; vd[1] = a.u[1]; vd[2] = a.u[2]; vd[3] = a.u[3];
            a.v = cv1; vd[4] = a.u[0]; vd[5] = a.u[1]; vd[6] = a.u[2]; vd[7] = a.u[3];
        }
        if (kb + 1 < kend) {   // prefetch next tile (overlaps compute below)
            int nb = (kb + 1) * 64;
            const ushortt* kp = Kg + (size_t)(nb + row) * 64 + seg * 16;
            ck0 = *reinterpret_cast<const uint4*>(kp);
            ck1 = *reinterpret_cast<const uint4*>(kp + 8);
            const ushortt* vp = Vg + (size_t)row * 4096 + nb + seg * 16;
            cv0 = *reinterpret_cast<const uint4*>(vp);
            cv1 = *reinterpret_cast<const uint4*>(vp + 8);
        }
        __syncthreads();

        // S^T = K Q'^T  (wave strip: 32 keys x 32 queries), exp2-domain
        floatx16 st = {};
        #pragma unroll
        for (int kc = 0; kc < 4; ++kc) {
            union { unsigned int u[4]; short8 s8; } af;
            const unsigned int* p = &smem[(32 * kh + l31) * 33 + kc * 8 + 4 * h];
            af.u[0] = p[0]; af.u[1] = p[1]; af.u[2] = p[2]; af.u[3] = p[3];
            st = __builtin_amdgcn_mfma_f32_32x32x16_bf16(af.s8, bq[kc], st, 0, 0, 0);
        }

        // online softmax over this wave's 32 keys for column q=l31
        float mx = st[0];
        #pragma unroll
        for (int r = 1; r < 16; ++r) mx = fmaxf(mx, st[r]);
        mx = fmaxf(mx, __shfl_xor(mx, 32));
        if (__any(mx > m_i)) {
            float mn = fmaxf(m_i, mx);
            float alpha = exp2f(m_i - mn);
            m_i = mn;
            l_i *= alpha;
            #pragma unroll
            for (int r = 0; r < 16; ++r) { ot0[r] *= alpha; ot1[r] *= alpha; }
        }
        float p[16], rs = 0.f;
        #pragma unroll
        for (int r = 0; r < 16; ++r) { p[r] = exp2f(st[r] - m_i); rs += p[r]; }
        rs += __shfl_xor(rs, 32);
        l_i += rs;

        // P: C-layout -> B-operand frags, fully in-register
        unsigned int pk[8], sp[8];
        #pragma unroll
        for (int i = 0; i < 8; ++i) pk[i] = f2bf_pk(p[2 * i], p[2 * i + 1]);
        #pragma unroll
        for (int i = 0; i < 8; ++i) sp[i] = (unsigned int)__shfl_xor((int)pk[i], 32);
        union { unsigned int u[4]; short8 s8; } pb0, pb1;
        pb0.u[0] = h ? sp[2] : pk[0]; pb0.u[1] = h ? sp[3] : pk[1];
        pb0.u[2] = h ? pk[2] : sp[0]; pb0.u[3] = h ? pk[3] : sp[1];
        pb1.u[0] = h ? sp[6] : pk[4]; pb1.u[1] = h ? sp[7] : pk[5];
        pb1.u[2] = h ? pk[6] : sp[4]; pb1.u[3] = h ? pk[7] : sp[5];

        // O^T += V^T P  (2 d-strips x 2 key-chunks)
        #pragma unroll
        for (int c = 0; c < 2; ++c) {
            union { unsigned int u[4]; short8 s8; } af;
            const unsigned int* p0 = &smem[2112 + l31 * 33 + 16 * kh + 8 * c + 4 * h];
            af.u[0] = p0[0]; af.u[1] = p0[1]; af.u[2] = p0[2]; af.u[3] = p0[3];
            ot0 = __builtin_amdgcn_mfma_f32_32x32x16_bf16(af.s8, c ? pb1.s8 : pb0.s8, ot0, 0, 0, 0);
            const unsigned int* p1 = &smem[2112 + (32 + l31) * 33 + 16 * kh + 8 * c + 4 * h];
            af.u[0] = p1[0]; af.u[1] = p1[1]; af.u[2] = p1[2]; af.u[3] = p1[3];
            ot1 = __builtin_amdgcn_mfma_f32_32x32x16_bf16(af.s8, c ? pb1.s8 : pb0.s8, ot1, 0, 0, 0);
        }
    }

    // ---- merge kh halves ----
    __syncthreads();
    if (h == 0) {
        smem[4160 + w * 32 + l31] = __float_as_uint(m_i);
        smem[4288 + w * 32 + l31] = __float_as_uint(l_i);
    }
    __syncthreads();
    int pw = 2 * (1 - kh) + qh;
    float m2 = __uint_as_float(smem[4160 + pw * 32 + l31]);
    float l2 = __uint_as_float(smem[4288 + pw * 32 + l31]);
    float mstar = fmaxf(m_i, m2);
    float wself = exp2f(m_i - mstar);
    float w2 = exp2f(m2 - mstar);
    float lm = wself * l_i + w2 * l2;
    float sc = (gridDim.z == 1) ? (wself / lm) : wself;
    if (gridDim.z > 1 && kh == 0 && h == 0) {
        float2 v; v.x = mstar; v.y = lm;
        ml[((size_t)s * 4 + b) * 4096 + n0 + 32 * qh + l31] = v;
    }
    float* om = reinterpret_cast<float*>(smem);
    if (kh == 0) {
        #pragma unroll
        for (int r = 0; r < 16; ++r) {
            int d0 = (r & 3) + 8 * (r >> 2) + 4 * h;
            om[(32 * qh + l31) * 65 + d0] = sc * ot0[r];
            om[(32 * qh + l31) * 65 + 32 + d0] = sc * ot1[r];
        }
    }
    __syncthreads();
    if (kh == 1) {
        #pragma unroll
        for (int r = 0; r < 16; ++r) {
            int d0 = (r & 3) + 8 * (r >> 2) + 4 * h;
            om[(32 * qh + l31) * 65 + d0] += sc * ot0[r];
            om[(32 * qh + l31) * 65 + 32 + d0] += sc * ot1[r];
        }
    }
    __syncthreads();
    {   // coalesced bf16 store
        int qq = tid >> 2, dsg = tid & 3;
        unsigned int pkk[8];
        #pragma unroll
        for (int j = 0; j < 8; ++j)
            pkk[j] = f2bf_pk(om[qq * 65 + dsg * 16 + 2 * j], om[qq * 65 + dsg * 16 + 2 * j + 1]);
        ushortt* base = (gridDim.z == 1)
            ? (Ob + ((size_t)b * 4096 + n0) * 64)
            : (Opart + (((size_t)s * 4 + b) * 4096 + n0) * 64);
        uint4* d4 = reinterpret_cast<uint4*>(base + (size_t)qq * 64 + dsg * 16);
        uint4 o0; o0.x = pkk[0]; o0.y = pkk[1]; o0.z = pkk[2]; o0.w = pkk[3];
        uint4 o1; o1.x = pkk[4]; o1.y = pkk[5]; o1.z = pkk[6]; o1.w = pkk[7];
        d4[0] = o0; d4[1] = o1;
    }
}

// ---------------------------------------------------------------------------
// Merge KV-split partials (bf16 Opart, exp2-domain m).
// ---------------------------------------------------------------------------
__global__ __launch_bounds__(256) void combine_kernel(
    const ushortt* __restrict__ Opart, const float2* __restrict__ ml,
    ushortt* __restrict__ Ob, int S) {
    const int tid = threadIdx.x;
    const int n0 = blockIdx.x * 64, b = blockIdx.y;
    const int row = n0 + (tid >> 2), dseg = tid & 3;
    float2 mls[4];
    float m = -1e30f;
    for (int s = 0; s < S; ++s) {
        mls[s] = ml[((size_t)s * 4 + b) * 4096 + row];
        m = fmaxf(m, mls[s].x);
    }
    float wgt[4], denom = 0.f;
    for (int s = 0; s < S; ++s) {
        wgt[s] = exp2f(mls[s].x - m);
        denom += wgt[s] * mls[s].y;
    }
    float inv = 1.0f / denom;
    float acc[16];
    #pragma unroll
    for (int j = 0; j < 16; ++j) acc[j] = 0.f;
    for (int s = 0; s < S; ++s) {
        const uint4* op = reinterpret_cast<const uint4*>(
            Opart + (((size_t)s * 4 + b) * 4096 + row) * 64 + dseg * 16);
        union { uint4 v; ushortt hh[8]; } u0, u1;
        u0.v = op[0]; u1.v = op[1];
        float ww = wgt[s];
        #pragma unroll
        for (int j = 0; j < 8; ++j) {
            acc[j] += ww * bf2f(u0.hh[j]);
            acc[8 + j] += ww * bf2f(u1.hh[j]);
        }
    }
    union { uint4 u[2]; unsigned int ww[8]; } pkv;
    #pragma unroll
    for (int j = 0; j < 8; ++j) pkv.ww[j] = f2bf_pk(acc[2 * j] * inv, acc[2 * j + 1] * inv);
    uint4* dst = reinterpret_cast<uint4*>(Ob + ((size_t)b * 4096 + row) * 64 + dseg * 16);
    dst[0] = pkv.u[0]; dst[1] = pkv.u[1];
}

// ---------------------------------------------------------------------------
// out = gamma*(Wv_sn O + bv) + x
// ---------------------------------------------------------------------------
__global__ __launch_bounds__(256) void proj_kernel(
    const ushortt* __restrict__ Ob, const ushortt* __restrict__ wvb,
    const float* __restrict__ bv, const float* __restrict__ gamma,
    const float* __restrict__ x, float* __restrict__ out) {
    const int tid = threadIdx.x;
    const int n0 = blockIdx.y * 64, c0 = blockIdx.x * 64, b = blockIdx.z;
    const int w = tid >> 6, lane = tid & 63, q = lane >> 4, l15 = lane & 15;

    short8 a0 = *reinterpret_cast<const short8*>(&wvb[(size_t)(c0 + 16 * w + l15) * 64 + q * 8]);
    short8 a1 = *reinterpret_cast<const short8*>(&wvb[(size_t)(c0 + 16 * w + l15) * 64 + 32 + q * 8]);
    floatx4 acc[4];
    #pragma unroll
    for (int t = 0; t < 4; ++t) acc[t] = (floatx4){0.f, 0.f, 0.f, 0.f};
    #pragma unroll
    for (int t = 0; t < 4; ++t) {
        const ushortt* ob = Ob + ((size_t)b * 4096 + n0 + 16 * t + l15) * 64;
        short8 b0 = *reinterpret_cast<const short8*>(ob + q * 8);
        short8 b1 = *reinterpret_cast<const short8*>(ob + 32 + q * 8);
        acc[t] = __builtin_amdgcn_mfma_f32_16x16x32_bf16(a0, b0, acc[t], 0, 0, 0);
        acc[t] = __builtin_amdgcn_mfma_f32_16x16x32_bf16(a1, b1, acc[t], 0, 0, 0);
    }
    float gm = gamma[0];
    #pragma unroll
    for (int t = 0; t < 4; ++t) {
        #pragma unroll
        for (int r = 0; r < 4; ++r) {
            int c = c0 + 16 * w + 4 * q + r;
            int n = n0 + 16 * t + l15;
            size_t idx = ((size_t)(b * 512 + c)) * 4096 + n;
            out[idx] = gm * (acc[t][r] + bv[c]) + x[idx];
        }
    }
}

// ---------------------------------------------------------------------------
extern "C" void kernel_launch(void* const* d_in, const int* in_sizes, int n_in,
                              void* d_out, int out_size, void* d_ws, size_t ws_size,
                              hipStream_t stream) {
    const float* x   = (const float*)d_in[0];
    const float* Wf  = (const float*)d_in[1];
    const float* bf_ = (const float*)d_in[2];
    const float* Wg  = (const float*)d_in[3];
    const float* bg_ = (const float*)d_in[4];
    const float* Wh  = (const float*)d_in[5];
    const float* bh_ = (const float*)d_in[6];
    const float* Wv  = (const float*)d_in[7];
    const float* bv_ = (const float*)d_in[8];
    const float* uf  = (const float*)d_in[9];
    const float* ug  = (const float*)d_in[10];
    const float* uh  = (const float*)d_in[11];
    const float* uv  = (const float*)d_in[12];
    const float* gm  = (const float*)d_in[13];
    float* out = (float*)d_out;

    char* ws = (char*)d_ws;
    float*   sig   = (float*)ws;                         // 256 B
    ushortt* wqkv  = (ushortt*)(ws + 256);               // 196608
    ushortt* wvb   = (ushortt*)(ws + 196864);            // 65536
    ushortt* Qb    = (ushortt*)(ws + 262400);            // 2 MB
    ushortt* Kb    = (ushortt*)(ws + 2359552);           // 2 MB
    ushortt* Vt    = (ushortt*)(ws + 4456704);           // 2 MB  [b][d][n]
    ushortt* Ob    = (ushortt*)(ws + 6553856);           // 2 MB
    float2*  ml    = (float2*)(ws + 8651008);            // 512 KB (S=4)
    ushortt* Opart = (ushortt*)(ws + 9175296);           // 8 MB bf16 (S=4)

    int S = (ws_size >= (size_t)17563904) ? 4 : 1;

    sigma_kernel<<<4, 256, 0, stream>>>(Wf, uf, Wg, ug, Wh, uh, Wv, uv, sig);
    prep_w_kernel<<<512, 256, 0, stream>>>(Wf, Wg, Wh, Wv, sig, wqkv, wvb);
    qkv_kernel<<<dim3(128, 4), 256, 0, stream>>>(x, wqkv, bf_, bg_, bh_, Qb, Kb, Vt);
    attn_kernel<<<dim3(64, 4, S), 256, 0, stream>>>(Qb, Kb, Vt, Opart, ml, Ob, 64 / S);
    if (S > 1) combine_kernel<<<dim3(64, 4), 256, 0, stream>>>(Opart, ml, Ob, S);
    proj_kernel<<<dim3(8, 64, 4), 256, 0, stream>>>(Ob, wvb, bv_, gm, x, out);
}